// Round 1
// baseline (232.965 us; speedup 1.0000x reference)
//
#include <hip/hip_runtime.h>

// TTTConv: depthwise causal conv1d, B=4, N=4096, D=2048, K=4, fp32.
// out[b,n,d] = bias[d] + sum_{k=0..3} w[d,k] * x[b, n-3+k, d]  (x[t<0]=0)
// states[b,d,k] = x[b, N-4+k, d]
// Memory-bound: 128 MiB in + 128 MiB out -> ~42 us roofline at 6.3 TB/s.

constexpr int B = 4, N = 4096, D = 2048, K = 4;
constexpr int T = 8;              // timesteps per thread
constexpr int BLK = 256;          // threads per block
constexpr int DV = D / 4;         // 512 float4 lanes across channels
constexpr int DBLKS = DV / BLK;   // 2 d-blocks per row
constexpr int NCHUNKS = N / T;    // 512 n-chunks

__global__ __launch_bounds__(BLK) void tttconv_main(
    const float* __restrict__ x, const float* __restrict__ w,
    const float* __restrict__ bias, float* __restrict__ out)
{
    int bid = blockIdx.x;
    int b = bid / (NCHUNKS * DBLKS);
    int rem = bid % (NCHUNKS * DBLKS);
    int nchunk = rem / DBLKS;
    int dblk = rem % DBLKS;
    int dv = dblk * BLK + threadIdx.x;   // 0..511
    int d = dv * 4;
    int n0 = nchunk * T;

    // w is (D,K) row-major: w[d+c][k] -> 16 contiguous floats at d*K
    const float4* w4 = (const float4*)(w + (size_t)d * K);
    float4 wr0 = w4[0];  // w[d+0][0..3]
    float4 wr1 = w4[1];  // w[d+1][0..3]
    float4 wr2 = w4[2];
    float4 wr3 = w4[3];
    float4 bv = *(const float4*)(bias + d);

    const float* xbase = x + ((size_t)b * N) * D + d;
    float4 xin[T + K - 1];
    if (n0 >= K - 1) {
        // fast path: no boundary
        #pragma unroll
        for (int j = 0; j < T + K - 1; ++j)
            xin[j] = *(const float4*)(xbase + (size_t)(n0 - (K - 1) + j) * D);
    } else {
        #pragma unroll
        for (int j = 0; j < T + K - 1; ++j) {
            int n = n0 - (K - 1) + j;
            xin[j] = (n >= 0) ? *(const float4*)(xbase + (size_t)n * D)
                              : make_float4(0.f, 0.f, 0.f, 0.f);
        }
    }

    float* obase = out + ((size_t)b * N) * D + d;
    #pragma unroll
    for (int t = 0; t < T; ++t) {
        float4 acc = bv;
        // channel c uses wr_c; input index n0+t-3+k -> xin[t+k]
        acc.x += wr0.x * xin[t + 0].x + wr0.y * xin[t + 1].x + wr0.z * xin[t + 2].x + wr0.w * xin[t + 3].x;
        acc.y += wr1.x * xin[t + 0].y + wr1.y * xin[t + 1].y + wr1.z * xin[t + 2].y + wr1.w * xin[t + 3].y;
        acc.z += wr2.x * xin[t + 0].z + wr2.y * xin[t + 1].z + wr2.z * xin[t + 2].z + wr2.w * xin[t + 3].z;
        acc.w += wr3.x * xin[t + 0].w + wr3.y * xin[t + 1].w + wr3.z * xin[t + 2].w + wr3.w * xin[t + 3].w;
        *(float4*)(obase + (size_t)(n0 + t) * D) = acc;
    }
}

__global__ void tttconv_states(const float* __restrict__ x, float* __restrict__ st)
{
    int idx = blockIdx.x * blockDim.x + threadIdx.x;  // over B*D*K = 32768
    if (idx >= B * D * K) return;
    int k = idx % K;
    int d = (idx / K) % D;
    int b = idx / (K * D);
    st[idx] = x[((size_t)b * N + (N - K + k)) * D + d];
}

extern "C" void kernel_launch(void* const* d_in, const int* in_sizes, int n_in,
                              void* d_out, int out_size, void* d_ws, size_t ws_size,
                              hipStream_t stream)
{
    const float* x    = (const float*)d_in[0];
    const float* w    = (const float*)d_in[1];
    const float* bias = (const float*)d_in[2];
    float* out = (float*)d_out;

    tttconv_main<<<B * NCHUNKS * DBLKS, BLK, 0, stream>>>(x, w, bias, out);

    float* st = out + (size_t)B * N * D;
    tttconv_states<<<(B * D * K + 255) / 256, 256, 0, stream>>>(x, st);
}